// Round 2
// baseline (394.905 us; speedup 1.0000x reference)
//
#include <hip/hip_runtime.h>
#include <hip/hip_bf16.h>
#include <hip/hip_cooperative_groups.h>

namespace cg = cooperative_groups;

#define N_NODES 50000
#define N_EDGES 800000
#define D 64
#define B 64
#define HL 128
#define OUT 32

#define CAP 64          // max in-degree capacity (Poisson(16): P(>=64) ~ 1e-18)
#define STP 72          // LDS transform tile row stride (ushorts)
#define ZROW N_NODES    // sentinel index (u16-safe: 50000 < 65536)

#define BINS 196        // ceil(N_NODES/256): coarse bins of 256 nodes (dst>>8)
#define EPB 2048        // edges per block in binA
#define LCAP 48         // per-(block,bin) LDS staging cap
#define BCAP 4608       // per-bin global region cap (mean 4082)

#define AB 391          // binA tiles
#define CB 3125         // cvt tiles (N*D/4/256)
#define MB 782          // mlp tiles (64 nodes each)

#define CVT_A 1563      // cvt tiles co-scheduled with binA
#define CVT_B (CB - CVT_A)

#define NT0A (AB + CVT_A)           // phase 0a tiles
#define NT0B (BINS + CVT_B + 1)     // phase 0b tiles (binB + cvt + init)

typedef __attribute__((ext_vector_type(8))) short          short8;
typedef __attribute__((ext_vector_type(8))) unsigned short ushort8_t;
typedef __attribute__((ext_vector_type(4))) float          floatx4;

// bf16 helpers (RNE pack, cheap unpack)
__device__ __forceinline__ unsigned short f2bf(float f)
{
    unsigned u = __float_as_uint(f);
    u = (u + 0x7FFFu + ((u >> 16) & 1u)) >> 16;
    return (unsigned short)u;
}
__device__ __forceinline__ float bf2f(unsigned short s)
{
    return __uint_as_float(((unsigned)s) << 16);
}
__device__ __forceinline__ float bfLO(unsigned u) { return __uint_as_float(u << 16); }
__device__ __forceinline__ float bfHI(unsigned u) { return __uint_as_float(u & 0xffff0000u); }

__device__ __forceinline__ int lower_bound_dev(const int* a, int n, int v)
{
    int lo = 0, hi = n;
    while (lo < hi) {
        int m = (lo + hi) >> 1;
        if (a[m] < v) lo = m + 1; else hi = m;
    }
    return lo;
}

__device__ __forceinline__ float sigmoidf_(float x) { return 1.0f / (1.0f + expf(-x)); }

// ---------------------------------------------------------------------------
// In-kernel gather of a wave's 16-node tile into its LDS transform tile.
// Wave processes 4 nodes at a time: group g = lane>>4 owns node n0+b*4+g,
// lane c = lane&15 owns dims 4c..4c+3 (uint2 = 8 B/lane). Buckets are
// ZROW-padded so overshoot rows add cached zeros. Loop trip = max over the
// 4 groups (shfl-xor max) -> wave-uniform.
// ---------------------------------------------------------------------------
__device__ __forceinline__ void gather16(
    const unsigned short* __restrict__ feat,
    const int*            __restrict__ cnt,
    const unsigned short* __restrict__ bucket,
    unsigned short*       stw,            // wave's LDS tile, 16 rows x STP
    int n0, int lane)
{
    const int g = lane >> 4;
    const int c = lane & 15;

#pragma unroll
    for (int b = 0; b < 4; ++b) {
        const int node = n0 + b * 4 + g;
        int deg = cnt[node];
        deg = (deg < CAP) ? deg : CAP;
        int m = (deg + 7) >> 3;
        {   // wave-max over the 4 groups
            int t1 = __shfl_xor(m, 16); m = (t1 > m) ? t1 : m;
            int t2 = __shfl_xor(m, 32); m = (t2 > m) ? t2 : m;
        }

        const unsigned short* bkt = bucket + (size_t)node * CAP;

        // self row
        uint2 u = *reinterpret_cast<const uint2*>(feat + (size_t)node * D + 4 * c);
        float a0 = bfLO(u.x), a1 = bfHI(u.x);
        float a2 = bfLO(u.y), a3 = bfHI(u.y);

        ushort8_t idx = *reinterpret_cast<const ushort8_t*>(bkt);
        for (int r = 0; r < m; ++r) {
            ushort8_t nxt = *reinterpret_cast<const ushort8_t*>(bkt + (r + 1) * 8);
#pragma unroll
            for (int j = 0; j < 8; ++j) {
                uint2 v = *reinterpret_cast<const uint2*>(
                    feat + (size_t)idx[j] * D + 4 * c);
                a0 += bfLO(v.x); a1 += bfHI(v.x);
                a2 += bfLO(v.y); a3 += bfHI(v.y);
            }
            idx = nxt;
        }

        uint2 o;
        o.x = (unsigned)f2bf(a0) | ((unsigned)f2bf(a1) << 16);
        o.y = (unsigned)f2bf(a2) | ((unsigned)f2bf(a3) << 16);
        *reinterpret_cast<uint2*>(stw + (b * 4 + g) * STP + 4 * c) = o;
    }
}

// ===========================================================================
// Cooperative mega-kernel: the whole pipeline in one dispatch.
//   P0a: binA (391 tiles) + cvt tiles [0,1563)
//   P0b: binB (196) + cvt tiles [1563,3125) + init (1)
//   P1 : fused gather+MLP layer 1 (782)
//   P2 : fused gather+MLP layer 2 + pool (782)
//   P3 : head (blocks 0..63)
// grid.sync() between phases (device-scope fence semantics).
// ===========================================================================
__global__ __launch_bounds__(256) void onekernel(
    const int*   __restrict__ ei,
    int*         __restrict__ bincnt,
    unsigned*    __restrict__ binbuf,
    const float* __restrict__ x,
    unsigned short* __restrict__ xb,
    const float* __restrict__ w1, const float* __restrict__ w2,
    const float* __restrict__ w3, const float* __restrict__ w4,
    unsigned short* __restrict__ wb,
    unsigned short* __restrict__ h1,
    float*       __restrict__ psum,
    int*         __restrict__ cnt,
    unsigned short* __restrict__ bucket,
    const int*   __restrict__ batch,
    const float* __restrict__ b1, const float* __restrict__ b2,
    const float* __restrict__ b3, const float* __restrict__ b4,
    const float* __restrict__ w_ih, const float* __restrict__ w_hh,
    const float* __restrict__ b_ih, const float* __restrict__ b_hh,
    const float* __restrict__ fc_w, const float* __restrict__ fc_b,
    const float* __restrict__ h0,  const float* __restrict__ c0,
    float* __restrict__ out_probs,
    float* __restrict__ out_h1,
    float* __restrict__ out_c1)
{
    // LDS union: binA = 39200 B (max) | binB = 33792 | mlp2 = 26112 | head = 3456
    __shared__ __align__(16) unsigned char smem[39232];

    cg::grid_group grid = cg::this_grid();

    const int t    = threadIdx.x;
    const int wv   = t >> 6;
    const int lane = t & 63;
    const int quad = lane >> 4;
    const int col  = lane & 15;

    // ---------------- Phase 0a: binA + cvt(part 1) ----------------
    {
        int* lcnt  = (int*)smem;                 // [BINS]
        int* gbase = lcnt + BINS;                // [BINS]
        unsigned* lbuf = (unsigned*)(gbase + BINS); // [BINS*LCAP]

        for (int tile = blockIdx.x; tile < NT0A; tile += gridDim.x) {
            if (tile < AB) {
                // ---- binA ----
                if (t < BINS) lcnt[t] = 0;
                __syncthreads();

                int base = tile * EPB;
#pragma unroll
                for (int i = 0; i < EPB / 256; ++i) {
                    int e = base + i * 256 + t;
                    if (e < N_EDGES) {
                        int s = ei[e];
                        int d = ei[N_EDGES + e];
                        int bin = d >> 8;
                        unsigned pk = (unsigned)s | ((unsigned)(d & 255) << 16);
                        int p = atomicAdd(&lcnt[bin], 1);
                        if (p < LCAP) {
                            lbuf[bin * LCAP + p] = pk;
                        } else {                  // statistically never
                            int q = atomicAdd(&bincnt[bin], 1);
                            if (q < BCAP) binbuf[bin * BCAP + q] = pk;
                        }
                    }
                }
                __syncthreads();

                if (t < BINS) {
                    int m = lcnt[t]; m = (m < LCAP) ? m : LCAP;
                    gbase[t] = (m > 0) ? atomicAdd(&bincnt[t], m) : 0;
                }
                __syncthreads();

                for (int b = wv; b < BINS; b += 4) {
                    int m = lcnt[b]; m = (m < LCAP) ? m : LCAP;
                    int gb = gbase[b];
                    for (int j = lane; j < m; j += 64)
                        if (gb + j < BCAP) binbuf[b * BCAP + gb + j] = lbuf[b * LCAP + j];
                }
                __syncthreads();      // protect lcnt/lbuf for next binA tile
            } else {
                // ---- cvt part 1 ----
                int cb = tile - AB;                      // [0, CVT_A)
                int i = cb * 256 + t;
                const float4 v = reinterpret_cast<const float4*>(x)[i];
                ushort4 o;
                o.x = f2bf(v.x); o.y = f2bf(v.y); o.z = f2bf(v.z); o.w = f2bf(v.w);
                reinterpret_cast<ushort4*>(xb)[i] = o;

                if (cb < 64) {                           // weights -> bf16
                    int j = cb * 256 + t;
                    int m = j >> 12, off = j & 4095;
                    const float* src = (m == 0) ? w1 : (m == 1) ? w2 : (m == 2) ? w3 : w4;
                    wb[j] = f2bf(src[off]);
                }
            }
        }
    }
    grid.sync();

    // ---------------- Phase 0b: binB + cvt(part 2) + init ----------------
    {
        int* lc = (int*)smem;                            // [256]
        unsigned short* lbkt = (unsigned short*)(smem + 1024); // [256*CAP] 32 KB

        for (int tile = blockIdx.x; tile < NT0B; tile += gridDim.x) {
            if (tile < BINS) {
                // ---- binB ----
                lc[t] = 0;
                {
                    ushort8_t fill = {ZROW, ZROW, ZROW, ZROW, ZROW, ZROW, ZROW, ZROW};
                    for (int idx = t; idx < 256 * CAP / 8; idx += 256)
                        reinterpret_cast<ushort8_t*>(lbkt)[idx] = fill;
                }
                __syncthreads();

                int bin = tile;
                int m = bincnt[bin]; m = (m < BCAP) ? m : BCAP;
                const unsigned* src = binbuf + bin * BCAP;
                for (int j = t; j < m; j += 256) {
                    unsigned pk = src[j];
                    int dlow = (pk >> 16) & 255;
                    int p = atomicAdd(&lc[dlow], 1);
                    if (p < CAP) lbkt[dlow * CAP + p] = (unsigned short)(pk & 0xFFFFu);
                }
                __syncthreads();

                int n0b = bin * 256;
                int n = n0b + t;
                if (n < N_NODES) cnt[n] = (lc[t] < CAP) ? lc[t] : CAP;

                for (int idx = t; idx < 256 * 8; idx += 256) {
                    int r = idx >> 3, c2 = idx & 7;
                    if (n0b + r < N_NODES)
                        *reinterpret_cast<ushort8_t*>(
                            bucket + (size_t)(n0b + r) * CAP + c2 * 8) =
                            *reinterpret_cast<const ushort8_t*>(&lbkt[r * CAP + c2 * 8]);
                }
                __syncthreads();      // protect lc/lbkt for next binB tile
            } else if (tile < BINS + CVT_B) {
                // ---- cvt part 2 ----
                int cb = CVT_A + (tile - BINS);          // [CVT_A, CB)
                int i = cb * 256 + t;
                const float4 v = reinterpret_cast<const float4*>(x)[i];
                ushort4 o;
                o.x = f2bf(v.x); o.y = f2bf(v.y); o.z = f2bf(v.z); o.w = f2bf(v.w);
                reinterpret_cast<ushort4*>(xb)[i] = o;
            } else {
                // ---- init ----
                if (t < D) {                             // sentinel zero rows
                    xb[(size_t)ZROW * D + t] = 0;
                    h1[(size_t)ZROW * D + t] = 0;
                }
#pragma unroll
                for (int k = 0; k < 16; ++k)             // psum[B*64] = 0
                    psum[t * 16 + k] = 0.0f;
            }
        }
    }
    grid.sync();

    // ---------------- Phase 1: fused gather + MLP layer 1 ----------------
    {
        unsigned short* stw = (unsigned short*)smem + wv * (16 * STP);
        const unsigned short* wAb = wb;
        const unsigned short* wBb = wb + 4096;

        float bAl[4], bBl[4];
#pragma unroll
        for (int tt = 0; tt < 4; ++tt) {
            bAl[tt] = b1[tt * 16 + col];
            bBl[tt] = b2[tt * 16 + col];
        }
        short8 WA[4][2], WB[4][2];
#pragma unroll
        for (int tt = 0; tt < 4; ++tt)
#pragma unroll
            for (int k = 0; k < 2; ++k) {
                WA[tt][k] = *reinterpret_cast<const short8*>(
                    wAb + (tt * 16 + col) * D + k * 32 + quad * 8);
                WB[tt][k] = *reinterpret_cast<const short8*>(
                    wBb + (tt * 16 + col) * D + k * 32 + quad * 8);
            }

        for (int tile = blockIdx.x; tile < MB; tile += gridDim.x) {
            const int n0 = (tile * 4 + wv) * 16;
            if (n0 < N_NODES) {
                gather16(xb, cnt, bucket, stw, n0, lane);

                short8 A0 = *reinterpret_cast<const short8*>(stw + col * STP + 0 * 32 + quad * 8);
                short8 A1 = *reinterpret_cast<const short8*>(stw + col * STP + 1 * 32 + quad * 8);

#pragma unroll
                for (int tt = 0; tt < 4; ++tt) {
                    floatx4 c = {0.0f, 0.0f, 0.0f, 0.0f};
                    c = __builtin_amdgcn_mfma_f32_16x16x32_bf16(A0, WA[tt][0], c, 0, 0, 0);
                    c = __builtin_amdgcn_mfma_f32_16x16x32_bf16(A1, WA[tt][1], c, 0, 0, 0);
#pragma unroll
                    for (int r = 0; r < 4; ++r) {
                        float v = fmaxf(c[r] + bAl[tt], 0.0f);
                        stw[(quad * 4 + r) * STP + tt * 16 + col] = f2bf(v);
                    }
                }

                short8 T0 = *reinterpret_cast<const short8*>(stw + col * STP + 0 * 32 + quad * 8);
                short8 T1 = *reinterpret_cast<const short8*>(stw + col * STP + 1 * 32 + quad * 8);

#pragma unroll
                for (int tt = 0; tt < 4; ++tt) {
                    floatx4 c = {0.0f, 0.0f, 0.0f, 0.0f};
                    c = __builtin_amdgcn_mfma_f32_16x16x32_bf16(T0, WB[tt][0], c, 0, 0, 0);
                    c = __builtin_amdgcn_mfma_f32_16x16x32_bf16(T1, WB[tt][1], c, 0, 0, 0);
#pragma unroll
                    for (int r = 0; r < 4; ++r) {
                        float v = fmaxf(c[r] + bBl[tt], 0.0f);
                        h1[(size_t)(n0 + quad * 4 + r) * D + tt * 16 + col] = f2bf(v);
                    }
                }
            }
        }
    }
    grid.sync();

    // ---------------- Phase 2: fused gather + MLP layer 2 + pool ----------------
    {
        unsigned short* stw = (unsigned short*)smem + wv * (16 * STP);
        float (*pt)[D + 1] = (float (*)[D + 1])(smem + 9216);
        int* sbatch = (int*)(smem + 9216 + 16640);
        const unsigned short* wAb = wb + 8192;
        const unsigned short* wBb = wb + 12288;

        float bAl[4], bBl[4];
#pragma unroll
        for (int tt = 0; tt < 4; ++tt) {
            bAl[tt] = b3[tt * 16 + col];
            bBl[tt] = b4[tt * 16 + col];
        }
        short8 WA[4][2], WB[4][2];
#pragma unroll
        for (int tt = 0; tt < 4; ++tt)
#pragma unroll
            for (int k = 0; k < 2; ++k) {
                WA[tt][k] = *reinterpret_cast<const short8*>(
                    wAb + (tt * 16 + col) * D + k * 32 + quad * 8);
                WB[tt][k] = *reinterpret_cast<const short8*>(
                    wBb + (tt * 16 + col) * D + k * 32 + quad * 8);
            }

        for (int tile = blockIdx.x; tile < MB; tile += gridDim.x) {
            const int bn0 = tile * 64;
            const int n0  = bn0 + wv * 16;
            const bool active = (n0 < N_NODES);

            if (t < 64) {
                int n = bn0 + t;
                sbatch[t] = (n < N_NODES) ? batch[n] : -1;
            }

            if (active) {
                gather16(h1, cnt, bucket, stw, n0, lane);

                short8 A0 = *reinterpret_cast<const short8*>(stw + col * STP + 0 * 32 + quad * 8);
                short8 A1 = *reinterpret_cast<const short8*>(stw + col * STP + 1 * 32 + quad * 8);

#pragma unroll
                for (int tt = 0; tt < 4; ++tt) {
                    floatx4 c = {0.0f, 0.0f, 0.0f, 0.0f};
                    c = __builtin_amdgcn_mfma_f32_16x16x32_bf16(A0, WA[tt][0], c, 0, 0, 0);
                    c = __builtin_amdgcn_mfma_f32_16x16x32_bf16(A1, WA[tt][1], c, 0, 0, 0);
#pragma unroll
                    for (int r = 0; r < 4; ++r) {
                        float v = fmaxf(c[r] + bAl[tt], 0.0f);
                        stw[(quad * 4 + r) * STP + tt * 16 + col] = f2bf(v);
                    }
                }

                short8 T0 = *reinterpret_cast<const short8*>(stw + col * STP + 0 * 32 + quad * 8);
                short8 T1 = *reinterpret_cast<const short8*>(stw + col * STP + 1 * 32 + quad * 8);

#pragma unroll
                for (int tt = 0; tt < 4; ++tt) {
                    floatx4 c = {0.0f, 0.0f, 0.0f, 0.0f};
                    c = __builtin_amdgcn_mfma_f32_16x16x32_bf16(T0, WB[tt][0], c, 0, 0, 0);
                    c = __builtin_amdgcn_mfma_f32_16x16x32_bf16(T1, WB[tt][1], c, 0, 0, 0);
#pragma unroll
                    for (int r = 0; r < 4; ++r) {
                        float v = fmaxf(c[r] + bBl[tt], 0.0f);
                        pt[wv * 16 + quad * 4 + r][tt * 16 + col] = v;
                    }
                }
            } else {
                for (int c2 = 0; c2 < 4; ++c2)
#pragma unroll
                    for (int r = 0; r < 4; ++r)
                        pt[wv * 16 + quad * 4 + r][c2 * 16 + col] = 0.0f;
            }
            __syncthreads();

            // segmented reduce over sorted batch
            {
                int q = t >> 6;
                int d = t & 63;
                float acc = 0.0f;
                int curg = sbatch[q * 16];
#pragma unroll
                for (int r = 0; r < 16; ++r) {
                    int row = q * 16 + r;
                    int g2 = sbatch[row];
                    float v = pt[row][d];
                    if (g2 != curg) {
                        if (curg >= 0) atomicAdd(&psum[curg * D + d], acc);
                        acc = 0.0f;
                        curg = g2;
                    }
                    acc += v;
                }
                if (curg >= 0) atomicAdd(&psum[curg * D + d], acc);
            }
            __syncthreads();          // protect pt/sbatch for next tile
        }
    }
    grid.sync();

    // ---------------- Phase 3: head (blocks 0..B-1) ----------------
    if (blockIdx.x < B) {
        float* sp    = (float*)smem;          // 64
        float* sh    = sp + D;                // 128
        float* gates = sh + HL;               // 512
        float* sh1   = gates + 4 * HL;        // 128
        float* slog  = sh1 + HL;              // 32

        int b = blockIdx.x;
        int j = t;

        if (j < D) {
            int start = lower_bound_dev(batch, N_NODES, b);
            int end   = lower_bound_dev(batch, N_NODES, b + 1);
            sp[j] = psum[b * D + j] / fmaxf((float)(end - start), 1.0f);
        } else if (j < D + HL) {
            sh[j - D] = h0[b * HL + (j - D)];
        }
        __syncthreads();

        for (int jj = j; jj < 4 * HL; jj += 256) {
            float acc = b_ih[jj] + b_hh[jj];
#pragma unroll
            for (int k = 0; k < D; ++k)  acc = fmaf(sp[k], w_ih[jj * D + k], acc);
#pragma unroll
            for (int k = 0; k < HL; ++k) acc = fmaf(sh[k], w_hh[jj * HL + k], acc);
            gates[jj] = acc;
        }
        __syncthreads();

        if (j < HL) {
            float ig = gates[j];
            float fg = gates[HL + j];
            float gg = gates[2 * HL + j];
            float og = gates[3 * HL + j];
            float c  = sigmoidf_(fg) * c0[b * HL + j] + sigmoidf_(ig) * tanhf(gg);
            float hv = sigmoidf_(og) * tanhf(c);
            out_c1[b * HL + j] = c;
            out_h1[b * HL + j] = hv;
            sh1[j] = hv;
        }
        __syncthreads();

        if (j < OUT) {
            float a = fc_b[j];
#pragma unroll
            for (int k = 0; k < HL; ++k) a = fmaf(sh1[k], fc_w[j * HL + k], a);
            slog[j] = a;
        }
        __syncthreads();

        if (j < OUT) {
            float m = -1e30f;
#pragma unroll
            for (int k = 0; k < OUT; ++k) m = fmaxf(m, slog[k]);
            float s = 0.0f;
#pragma unroll
            for (int k = 0; k < OUT; ++k) s += expf(slog[k] - m);
            out_probs[b * OUT + j] = expf(slog[j] - m) / s;
        }
    }
}

// ===========================================================================
// Fallback path: the proven 5-dispatch pipeline (used only if cooperative
// launch is unavailable).
// ===========================================================================
__global__ __launch_bounds__(256) void fused_pro_kernel(
    const int*   __restrict__ ei,
    int*         __restrict__ bincnt,
    unsigned*    __restrict__ binbuf,
    const float* __restrict__ x, unsigned short* __restrict__ xb,
    const float* __restrict__ w1, const float* __restrict__ w2,
    const float* __restrict__ w3, const float* __restrict__ w4,
    unsigned short* __restrict__ wb,
    unsigned short* __restrict__ h1,
    float*       __restrict__ psum)
{
    __shared__ int      lcnt[BINS];
    __shared__ int      gbase[BINS];
    __shared__ unsigned lbuf[BINS * LCAP];

    int t = threadIdx.x;

    if (blockIdx.x < AB) {
        if (t < BINS) lcnt[t] = 0;
        __syncthreads();

        int base = blockIdx.x * EPB;
#pragma unroll
        for (int i = 0; i < EPB / 256; ++i) {
            int e = base + i * 256 + t;
            if (e < N_EDGES) {
                int s = ei[e];
                int d = ei[N_EDGES + e];
                int bin = d >> 8;
                unsigned pk = (unsigned)s | ((unsigned)(d & 255) << 16);
                int p = atomicAdd(&lcnt[bin], 1);
                if (p < LCAP) {
                    lbuf[bin * LCAP + p] = pk;
                } else {
                    int q = atomicAdd(&bincnt[bin], 1);
                    if (q < BCAP) binbuf[bin * BCAP + q] = pk;
                }
            }
        }
        __syncthreads();

        if (t < BINS) {
            int m = lcnt[t]; m = (m < LCAP) ? m : LCAP;
            gbase[t] = (m > 0) ? atomicAdd(&bincnt[t], m) : 0;
        }
        __syncthreads();

        int wv = t >> 6, lane = t & 63;
        for (int b = wv; b < BINS; b += 4) {
            int m = lcnt[b]; m = (m < LCAP) ? m : LCAP;
            int gb = gbase[b];
            for (int j = lane; j < m; j += 64)
                if (gb + j < BCAP) binbuf[b * BCAP + gb + j] = lbuf[b * LCAP + j];
        }
    } else if (blockIdx.x < AB + CB) {
        int cb = blockIdx.x - AB;
        int i = cb * 256 + t;
        const float4 v = reinterpret_cast<const float4*>(x)[i];
        ushort4 o;
        o.x = f2bf(v.x); o.y = f2bf(v.y); o.z = f2bf(v.z); o.w = f2bf(v.w);
        reinterpret_cast<ushort4*>(xb)[i] = o;

        if (cb < 64) {
            int j = cb * 256 + t;
            int m = j >> 12, off = j & 4095;
            const float* src = (m == 0) ? w1 : (m == 1) ? w2 : (m == 2) ? w3 : w4;
            wb[j] = f2bf(src[off]);
        }
    } else {
        if (t < D) {
            xb[(size_t)ZROW * D + t] = 0;
            h1[(size_t)ZROW * D + t] = 0;
        }
#pragma unroll
        for (int k = 0; k < 16; ++k)
            psum[t * 16 + k] = 0.0f;
    }
}

__global__ __launch_bounds__(256) void binB_kernel(
    const int*      __restrict__ bincnt,
    const unsigned* __restrict__ binbuf,
    int*            __restrict__ cnt,
    unsigned short* __restrict__ bucket)
{
    __shared__ int            lc[256];
    __shared__ unsigned short lbkt[256 * CAP];

    int t = threadIdx.x;
    lc[t] = 0;
    {
        ushort8_t fill = {ZROW, ZROW, ZROW, ZROW, ZROW, ZROW, ZROW, ZROW};
        for (int idx = t; idx < 256 * CAP / 8; idx += 256)
            reinterpret_cast<ushort8_t*>(lbkt)[idx] = fill;
    }
    __syncthreads();

    int bin = blockIdx.x;
    int m = bincnt[bin]; m = (m < BCAP) ? m : BCAP;
    const unsigned* src = binbuf + bin * BCAP;
    for (int j = t; j < m; j += 256) {
        unsigned pk = src[j];
        int dlow = (pk >> 16) & 255;
        int p = atomicAdd(&lc[dlow], 1);
        if (p < CAP) lbkt[dlow * CAP + p] = (unsigned short)(pk & 0xFFFFu);
    }
    __syncthreads();

    int n0 = bin * 256;
    int n = n0 + t;
    if (n < N_NODES) cnt[n] = (lc[t] < CAP) ? lc[t] : CAP;

    for (int idx = t; idx < 256 * 8; idx += 256) {
        int r = idx >> 3, c = idx & 7;
        if (n0 + r < N_NODES)
            *reinterpret_cast<ushort8_t*>(
                bucket + (size_t)(n0 + r) * CAP + c * 8) =
                *reinterpret_cast<const ushort8_t*>(&lbkt[r * CAP + c * 8]);
    }
}

__global__ __launch_bounds__(256) void gmlp_kernel(
    const unsigned short* __restrict__ feat,
    const int*            __restrict__ cnt,
    const unsigned short* __restrict__ bucket,
    const unsigned short* __restrict__ wAb,
    const float*          __restrict__ bA,
    const unsigned short* __restrict__ wBb,
    const float*          __restrict__ bB,
    unsigned short*       __restrict__ outp)
{
    __shared__ __align__(16) unsigned short st[4][16 * STP];

    const int wv   = threadIdx.x >> 6;
    const int lane = threadIdx.x & 63;
    const int quad = lane >> 4;
    const int col  = lane & 15;

    const int n0 = (blockIdx.x * 4 + wv) * 16;
    if (n0 >= N_NODES) return;

    float bAl[4], bBl[4];
#pragma unroll
    for (int t = 0; t < 4; ++t) {
        bAl[t] = bA[t * 16 + col];
        bBl[t] = bB[t * 16 + col];
    }

    short8 WA[4][2], WB[4][2];
#pragma unroll
    for (int t = 0; t < 4; ++t)
#pragma unroll
        for (int k = 0; k < 2; ++k) {
            WA[t][k] = *reinterpret_cast<const short8*>(
                wAb + (t * 16 + col) * D + k * 32 + quad * 8);
            WB[t][k] = *reinterpret_cast<const short8*>(
                wBb + (t * 16 + col) * D + k * 32 + quad * 8);
        }

    unsigned short* stw = &st[wv][0];

    gather16(feat, cnt, bucket, stw, n0, lane);

    short8 A0 = *reinterpret_cast<const short8*>(stw + col * STP + 0 * 32 + quad * 8);
    short8 A1 = *reinterpret_cast<const short8*>(stw + col * STP + 1 * 32 + quad * 8);

#pragma unroll
    for (int t = 0; t < 4; ++t) {
        floatx4 c = {0.0f, 0.0f, 0.0f, 0.0f};
        c = __builtin_amdgcn_mfma_f32_16x16x32_bf16(A0, WA[t][0], c, 0, 0, 0);
        c = __builtin_amdgcn_mfma_f32_16x16x32_bf16(A1, WA[t][1], c, 0, 0, 0);
#pragma unroll
        for (int r = 0; r < 4; ++r) {
            float v = fmaxf(c[r] + bAl[t], 0.0f);
            stw[(quad * 4 + r) * STP + t * 16 + col] = f2bf(v);
        }
    }

    short8 T0 = *reinterpret_cast<const short8*>(stw + col * STP + 0 * 32 + quad * 8);
    short8 T1 = *reinterpret_cast<const short8*>(stw + col * STP + 1 * 32 + quad * 8);

#pragma unroll
    for (int t = 0; t < 4; ++t) {
        floatx4 c = {0.0f, 0.0f, 0.0f, 0.0f};
        c = __builtin_amdgcn_mfma_f32_16x16x32_bf16(T0, WB[t][0], c, 0, 0, 0);
        c = __builtin_amdgcn_mfma_f32_16x16x32_bf16(T1, WB[t][1], c, 0, 0, 0);
#pragma unroll
        for (int r = 0; r < 4; ++r) {
            float v = fmaxf(c[r] + bBl[t], 0.0f);
            outp[(size_t)(n0 + quad * 4 + r) * D + t * 16 + col] = f2bf(v);
        }
    }
}

__global__ __launch_bounds__(256) void g2mlp_pool_kernel(
    const unsigned short* __restrict__ feat,
    const int*            __restrict__ cnt,
    const unsigned short* __restrict__ bucket,
    const unsigned short* __restrict__ wAb,
    const float*          __restrict__ bA,
    const unsigned short* __restrict__ wBb,
    const float*          __restrict__ bB,
    const int*            __restrict__ batch,
    float*                __restrict__ psum)
{
    __shared__ __align__(16) unsigned short st[4][16 * STP];
    __shared__ float pt[64][D + 1];
    __shared__ int   sbatch[64];

    const int tid  = threadIdx.x;
    const int wv   = tid >> 6;
    const int lane = tid & 63;
    const int quad = lane >> 4;
    const int col  = lane & 15;

    const int bn0 = blockIdx.x * 64;
    const int n0  = bn0 + wv * 16;
    const bool active = (n0 < N_NODES);

    if (tid < 64) {
        int n = bn0 + tid;
        sbatch[tid] = (n < N_NODES) ? batch[n] : -1;
    }

    if (active) {
        float bAl[4], bBl[4];
#pragma unroll
        for (int t = 0; t < 4; ++t) {
            bAl[t] = bA[t * 16 + col];
            bBl[t] = bB[t * 16 + col];
        }

        short8 WA[4][2], WB[4][2];
#pragma unroll
        for (int t = 0; t < 4; ++t)
#pragma unroll
            for (int k = 0; k < 2; ++k) {
                WA[t][k] = *reinterpret_cast<const short8*>(
                    wAb + (t * 16 + col) * D + k * 32 + quad * 8);
                WB[t][k] = *reinterpret_cast<const short8*>(
                    wBb + (t * 16 + col) * D + k * 32 + quad * 8);
            }

        unsigned short* stw = &st[wv][0];

        gather16(feat, cnt, bucket, stw, n0, lane);

        short8 A0 = *reinterpret_cast<const short8*>(stw + col * STP + 0 * 32 + quad * 8);
        short8 A1 = *reinterpret_cast<const short8*>(stw + col * STP + 1 * 32 + quad * 8);

#pragma unroll
        for (int t = 0; t < 4; ++t) {
            floatx4 c = {0.0f, 0.0f, 0.0f, 0.0f};
            c = __builtin_amdgcn_mfma_f32_16x16x32_bf16(A0, WA[t][0], c, 0, 0, 0);
            c = __builtin_amdgcn_mfma_f32_16x16x32_bf16(A1, WA[t][1], c, 0, 0, 0);
#pragma unroll
            for (int r = 0; r < 4; ++r) {
                float v = fmaxf(c[r] + bAl[t], 0.0f);
                stw[(quad * 4 + r) * STP + t * 16 + col] = f2bf(v);
            }
        }

        short8 T0 = *reinterpret_cast<const short8*>(stw + col * STP + 0 * 32 + quad * 8);
        short8 T1 = *reinterpret_cast<const short8*>(stw + col * STP + 1 * 32 + quad * 8);

#pragma unroll
        for (int t = 0; t < 4; ++t) {
            floatx4 c = {0.0f, 0.0f, 0.0f, 0.0f};
            c = __builtin_amdgcn_mfma_f32_16x16x32_bf16(T0, WB[t][0], c, 0, 0, 0);
            c = __builtin_amdgcn_mfma_f32_16x16x32_bf16(T1, WB[t][1], c, 0, 0, 0);
#pragma unroll
            for (int r = 0; r < 4; ++r) {
                float v = fmaxf(c[r] + bBl[t], 0.0f);
                pt[wv * 16 + quad * 4 + r][t * 16 + col] = v;
            }
        }
    } else {
        for (int c = 0; c < 4; ++c)
#pragma unroll
            for (int r = 0; r < 4; ++r)
                pt[wv * 16 + quad * 4 + r][c * 16 + col] = 0.0f;
    }
    __syncthreads();

    int q = tid >> 6;
    int d = tid & 63;
    float acc = 0.0f;
    int curg = sbatch[q * 16];
#pragma unroll
    for (int r = 0; r < 16; ++r) {
        int row = q * 16 + r;
        int g = sbatch[row];
        float v = pt[row][d];
        if (g != curg) {
            if (curg >= 0) atomicAdd(&psum[curg * D + d], acc);
            acc = 0.0f;
            curg = g;
        }
        acc += v;
    }
    if (curg >= 0) atomicAdd(&psum[curg * D + d], acc);
}

__global__ __launch_bounds__(512) void head_kernel(
    const float* __restrict__ psum,
    const int*   __restrict__ batch,
    const float* __restrict__ w_ih,
    const float* __restrict__ w_hh,
    const float* __restrict__ b_ih,
    const float* __restrict__ b_hh,
    const float* __restrict__ fc_w,
    const float* __restrict__ fc_b,
    const float* __restrict__ h0,
    const float* __restrict__ c0,
    float*       __restrict__ out_probs,
    float*       __restrict__ out_h1,
    float*       __restrict__ out_c1)
{
    int b = blockIdx.x;
    int j = threadIdx.x;

    __shared__ float sp[D];
    __shared__ float sh[HL];
    __shared__ float gates[4 * HL];
    __shared__ float sh1[HL];
    __shared__ float slog[OUT];

    if (j < D) {
        int start = lower_bound_dev(batch, N_NODES, b);
        int end   = lower_bound_dev(batch, N_NODES, b + 1);
        sp[j] = psum[b * D + j] / fmaxf((float)(end - start), 1.0f);
    } else if (j < D + HL) {
        sh[j - D] = h0[b * HL + (j - D)];
    }
    __syncthreads();

    {
        float acc = b_ih[j] + b_hh[j];
#pragma unroll
        for (int k = 0; k < D; ++k)  acc = fmaf(sp[k], w_ih[j * D + k], acc);
#pragma unroll
        for (int k = 0; k < HL; ++k) acc = fmaf(sh[k], w_hh[j * HL + k], acc);
        gates[j] = acc;
    }
    __syncthreads();

    if (j < HL) {
        float ig = gates[j];
        float fg = gates[HL + j];
        float gg = gates[2 * HL + j];
        float og = gates[3 * HL + j];
        float c  = sigmoidf_(fg) * c0[b * HL + j] + sigmoidf_(ig) * tanhf(gg);
        float hv = sigmoidf_(og) * tanhf(c);
        out_c1[b * HL + j] = c;
        out_h1[b * HL + j] = hv;
        sh1[j] = hv;
    }
    __syncthreads();

    if (j < OUT) {
        float a = fc_b[j];
#pragma unroll
        for (int k = 0; k < HL; ++k) a = fmaf(sh1[k], fc_w[j * HL + k], a);
        slog[j] = a;
    }
    __syncthreads();

    if (j < OUT) {
        float m = -1e30f;
#pragma unroll
        for (int k = 0; k < OUT; ++k) m = fmaxf(m, slog[k]);
        float s = 0.0f;
#pragma unroll
        for (int k = 0; k < OUT; ++k) s += expf(slog[k] - m);
        out_probs[b * OUT + j] = expf(slog[j] - m) / s;
    }
}

// ---------------------------------------------------------------------------
extern "C" void kernel_launch(void* const* d_in, const int* in_sizes, int n_in,
                              void* d_out, int out_size, void* d_ws, size_t ws_size,
                              hipStream_t stream)
{
    const float* x     = (const float*)d_in[0];
    const int*   ei    = (const int*)  d_in[1];
    const int*   batch = (const int*)  d_in[2];
    const float* w1    = (const float*)d_in[3];
    const float* b1    = (const float*)d_in[4];
    const float* w2    = (const float*)d_in[5];
    const float* b2    = (const float*)d_in[6];
    const float* w3    = (const float*)d_in[7];
    const float* b3    = (const float*)d_in[8];
    const float* w4    = (const float*)d_in[9];
    const float* b4    = (const float*)d_in[10];
    const float* w_ih  = (const float*)d_in[11];
    const float* w_hh  = (const float*)d_in[12];
    const float* b_ih  = (const float*)d_in[13];
    const float* b_hh  = (const float*)d_in[14];
    const float* fc_w  = (const float*)d_in[15];
    const float* fc_b  = (const float*)d_in[16];
    const float* h0    = (const float*)d_in[17];
    const float* c0    = (const float*)d_in[18];

    const size_t NR = (size_t)N_NODES + 16;
    int* bincnt = (int*)d_ws;                                 // 256 ints
    int* cnt    = bincnt + 256;                               // N ints
    unsigned* binbuf = (unsigned*)(cnt + N_NODES);            // BINS*BCAP
    unsigned short* bucket = (unsigned short*)(binbuf + (size_t)BINS * BCAP);
    unsigned short* xb = bucket + (size_t)N_NODES * CAP;      // [NR,64] bf16
    unsigned short* g  = xb + NR * D;                         // [NR,64] (unused)
    unsigned short* h1 = g  + NR * D;                         // [NR,64] mlp1 out
    unsigned short* wb = h1 + NR * D;                         // 4 x [64,64] bf16
    float* psum = (float*)(wb + 4 * D * D);                   // [B,64]
    (void)g;

    float* out_probs = (float*)d_out;
    float* out_h1    = out_probs + B * OUT;
    float* out_c1    = out_h1 + B * HL;

    hipMemsetAsync(bincnt, 0, 256 * sizeof(int), stream);

    // grid size for cooperative residency (cached)
    static int g_blocks = 0;
    if (g_blocks == 0) {
        int maxB = 0;
        hipError_t oe = hipOccupancyMaxActiveBlocksPerMultiprocessor(
            &maxB, (const void*)onekernel, 256, 0);
        if (oe != hipSuccess || maxB < 1) maxB = 1;
        long gsz = (long)maxB * 256;          // 256 CUs on MI355X
        if (gsz > 1024) gsz = 1024;
        if (gsz < 64)   gsz = 64;
        g_blocks = (int)gsz;
    }

    {
        const int*   ei_    = ei;
        int*         bincnt_ = bincnt;
        unsigned*    binbuf_ = binbuf;
        const float* x_     = x;
        unsigned short* xb_ = xb;
        const float* w1_ = w1; const float* w2_ = w2;
        const float* w3_ = w3; const float* w4_ = w4;
        unsigned short* wb_ = wb;
        unsigned short* h1_ = h1;
        float*       psum_ = psum;
        int*         cnt_  = cnt;
        unsigned short* bucket_ = bucket;
        const int*   batch_ = batch;
        const float* b1_ = b1; const float* b2_ = b2;
        const float* b3_ = b3; const float* b4_ = b4;
        const float* wih_ = w_ih; const float* whh_ = w_hh;
        const float* bih_ = b_ih; const float* bhh_ = b_hh;
        const float* fcw_ = fc_w; const float* fcb_ = fc_b;
        const float* h0_ = h0; const float* c0_ = c0;
        float* op_ = out_probs; float* oh_ = out_h1; float* oc_ = out_c1;

        void* kargs[] = {
            (void*)&ei_, (void*)&bincnt_, (void*)&binbuf_, (void*)&x_, (void*)&xb_,
            (void*)&w1_, (void*)&w2_, (void*)&w3_, (void*)&w4_, (void*)&wb_,
            (void*)&h1_, (void*)&psum_, (void*)&cnt_, (void*)&bucket_, (void*)&batch_,
            (void*)&b1_, (void*)&b2_, (void*)&b3_, (void*)&b4_,
            (void*)&wih_, (void*)&whh_, (void*)&bih_, (void*)&bhh_,
            (void*)&fcw_, (void*)&fcb_, (void*)&h0_, (void*)&c0_,
            (void*)&op_, (void*)&oh_, (void*)&oc_
        };

        hipError_t err = hipLaunchCooperativeKernel(
            (const void*)onekernel, dim3(g_blocks), dim3(256), kargs, 0, stream);

        if (err == hipSuccess) return;
    }

    // -------- fallback: proven 5-dispatch pipeline --------
    const int mb = (N_NODES / 16 + 3) / 4;           // 782
    fused_pro_kernel<<<AB + CB + 1, 256, 0, stream>>>(
        ei, bincnt, binbuf, x, xb, w1, w2, w3, w4, wb, h1, psum);
    binB_kernel<<<BINS, 256, 0, stream>>>(bincnt, binbuf, cnt, bucket);
    gmlp_kernel<<<mb, 256, 0, stream>>>(xb, cnt, bucket, wb, b1, wb + 4096, b2, h1);
    g2mlp_pool_kernel<<<mb, 256, 0, stream>>>(h1, cnt, bucket,
                                              wb + 8192, b3, wb + 12288, b4,
                                              batch, psum);
    head_kernel<<<B, 512, 0, stream>>>(psum, batch, w_ih, w_hh, b_ih, b_hh,
                                       fc_w, fc_b, h0, c0,
                                       out_probs, out_h1, out_c1);
}

// Round 3
// 199.035 us; speedup vs baseline: 1.9841x; 1.9841x over previous
//
#include <hip/hip_runtime.h>
#include <hip/hip_bf16.h>

#define N_NODES 50000
#define N_EDGES 800000
#define D 64
#define B 64
#define HL 128
#define OUT 32

#define CAP 64          // max in-degree capacity (Poisson(16): P(>=64) ~ 1e-18)
#define STP 72          // LDS transform tile row stride (ushorts)
#define ZROW N_NODES    // sentinel index (u16-safe: 50000 < 65536)

#define BINS 196        // ceil(N_NODES/256): coarse bins of 256 nodes (dst>>8)
#define EPB 2048        // edges per block in binA
#define LCAP 48         // per-(block,bin) LDS staging cap
#define BCAP 4608       // per-bin global region cap (mean 4082)

#define AB 391          // binA blocks
#define CB 3125         // cvt blocks (N*D/4/256)
#define MB 782          // mlp blocks (64 nodes each)

typedef __attribute__((ext_vector_type(8))) short          short8;
typedef __attribute__((ext_vector_type(8))) unsigned short ushort8_t;
typedef __attribute__((ext_vector_type(4))) float          floatx4;

// bf16 helpers (RNE pack, cheap unpack)
__device__ __forceinline__ unsigned short f2bf(float f)
{
    unsigned u = __float_as_uint(f);
    u = (u + 0x7FFFu + ((u >> 16) & 1u)) >> 16;
    return (unsigned short)u;
}
__device__ __forceinline__ float bf2f(unsigned short s)
{
    return __uint_as_float(((unsigned)s) << 16);
}
__device__ __forceinline__ float bfLO(unsigned u) { return __uint_as_float(u << 16); }
__device__ __forceinline__ float bfHI(unsigned u) { return __uint_as_float(u & 0xffff0000u); }

// ---------------------------------------------------------------------------
// Fused prologue, block-range roles (independent work overlaps in 1 dispatch):
//   [0, AB)        : binA — bin edges by dst>>8 via LDS staging
//   [AB, AB+CB)    : cvt x -> bf16 (first 64 also convert MLP weights)
//   AB+CB          : init — sentinel zero rows + psum zero
// bincnt is zeroed by a prior 1KB memset.
// ---------------------------------------------------------------------------
__global__ __launch_bounds__(256) void fused_pro_kernel(
    const int*   __restrict__ ei,
    int*         __restrict__ bincnt,
    unsigned*    __restrict__ binbuf,
    const float* __restrict__ x, unsigned short* __restrict__ xb,
    const float* __restrict__ w1, const float* __restrict__ w2,
    const float* __restrict__ w3, const float* __restrict__ w4,
    unsigned short* __restrict__ wb,
    unsigned short* __restrict__ h1,
    float*       __restrict__ psum)
{
    __shared__ int      lcnt[BINS];
    __shared__ int      gbase[BINS];
    __shared__ unsigned lbuf[BINS * LCAP];   // 37.6 KB

    int t = threadIdx.x;

    if (blockIdx.x < AB) {
        // ---------------- binA ----------------
        if (t < BINS) lcnt[t] = 0;
        __syncthreads();

        int base = blockIdx.x * EPB;
#pragma unroll
        for (int i = 0; i < EPB / 256; ++i) {
            int e = base + i * 256 + t;
            if (e < N_EDGES) {
                int s = ei[e];
                int d = ei[N_EDGES + e];
                int bin = d >> 8;
                unsigned pk = (unsigned)s | ((unsigned)(d & 255) << 16);
                int p = atomicAdd(&lcnt[bin], 1);
                if (p < LCAP) {
                    lbuf[bin * LCAP + p] = pk;
                } else {                          // statistically never
                    int q = atomicAdd(&bincnt[bin], 1);
                    if (q < BCAP) binbuf[bin * BCAP + q] = pk;
                }
            }
        }
        __syncthreads();

        if (t < BINS) {
            int m = lcnt[t]; m = (m < LCAP) ? m : LCAP;
            gbase[t] = (m > 0) ? atomicAdd(&bincnt[t], m) : 0;
        }
        __syncthreads();

        int wv = t >> 6, lane = t & 63;
        for (int b = wv; b < BINS; b += 4) {
            int m = lcnt[b]; m = (m < LCAP) ? m : LCAP;
            int gb = gbase[b];
            for (int j = lane; j < m; j += 64)
                if (gb + j < BCAP) binbuf[b * BCAP + gb + j] = lbuf[b * LCAP + j];
        }
    } else if (blockIdx.x < AB + CB) {
        // ---------------- cvt ----------------
        int cb = blockIdx.x - AB;
        int i = cb * 256 + t;                    // i < N*D/4
        const float4 v = reinterpret_cast<const float4*>(x)[i];
        ushort4 o;
        o.x = f2bf(v.x); o.y = f2bf(v.y); o.z = f2bf(v.z); o.w = f2bf(v.w);
        reinterpret_cast<ushort4*>(xb)[i] = o;

        if (cb < 64) {                           // 64*256 = 4*4096
            int j = cb * 256 + t;
            int m = j >> 12, off = j & 4095;
            const float* src = (m == 0) ? w1 : (m == 1) ? w2 : (m == 2) ? w3 : w4;
            wb[j] = f2bf(src[off]);
        }
    } else {
        // ---------------- init ----------------
        if (t < D) {                             // sentinel zero rows
            xb[(size_t)ZROW * D + t] = 0;
            h1[(size_t)ZROW * D + t] = 0;
        }
#pragma unroll
        for (int k = 0; k < 16; ++k)             // psum[B*64] = 0
            psum[t * 16 + k] = 0.0f;
    }
}

// ---------------------------------------------------------------------------
// Per-block LDS bucket build: the block's 64 nodes are one quarter of one
// 256-node bin. Scan the bin's packed-edge region once, keep entries whose
// dlow falls in our quarter. Rows pre-filled with ZROW -> branchless gather.
// Replaces the old 196-block binB dispatch + global bucket round-trip.
// Must be called by ALL 256 threads (contains __syncthreads).
// ---------------------------------------------------------------------------
__device__ __forceinline__ void build_bucket64(
    const int*      __restrict__ bincnt,
    const unsigned* __restrict__ binbuf,
    unsigned short* lbkt,     // [64*CAP + 16] LDS
    int*            lc,       // [64] LDS
    int bn0, int t)
{
    {
        ushort8_t fill = {ZROW, ZROW, ZROW, ZROW, ZROW, ZROW, ZROW, ZROW};
        reinterpret_cast<ushort8_t*>(lbkt)[t]       = fill;
        reinterpret_cast<ushort8_t*>(lbkt)[t + 256] = fill;
    }
    if (t < 64) lc[t] = 0;
    __syncthreads();

    const int bin = bn0 >> 8;
    const int q   = (bn0 >> 6) & 3;              // quarter within the bin
    int m = bincnt[bin]; m = (m < BCAP) ? m : BCAP;
    const unsigned* src = binbuf + bin * BCAP;
    for (int j = t; j < m; j += 256) {
        unsigned pk = src[j];
        int dlow = (pk >> 16) & 255;
        if ((dlow >> 6) == q) {
            int r = dlow & 63;
            int p = atomicAdd(&lc[r], 1);
            if (p < CAP) lbkt[r * CAP + p] = (unsigned short)(pk & 0xFFFFu);
        }
    }
    __syncthreads();
}

// ---------------------------------------------------------------------------
// Gather of a wave's 16-node tile into its LDS transform tile, indices from
// the block-local LDS bucket. Wave processes 4 nodes at a time: group
// g = lane>>4 owns node bn0+wv*16+b*4+g, lane c = lane&15 owns dims
// 4c..4c+3 (uint2 = 8 B/lane). Bucket rows ZROW-padded -> overshoot rows
// add cached zeros. Loop trip = max over the 4 groups (shfl-xor max).
// ---------------------------------------------------------------------------
__device__ __forceinline__ void gather16_lds(
    const unsigned short* __restrict__ feat,
    const unsigned short* lbkt,          // [64*CAP] LDS (+pad)
    const int*            lc,            // [64] LDS
    unsigned short*       stw,           // wave's LDS tile, 16 rows x STP
    int bn0, int wv, int lane)
{
    const int g = lane >> 4;
    const int c = lane & 15;

#pragma unroll
    for (int b = 0; b < 4; ++b) {
        const int rloc = wv * 16 + b * 4 + g;
        const int node = bn0 + rloc;
        int deg = lc[rloc];
        deg = (deg < CAP) ? deg : CAP;
        int m = (deg + 7) >> 3;
        {   // wave-max over the 4 groups
            int t1 = __shfl_xor(m, 16); m = (t1 > m) ? t1 : m;
            int t2 = __shfl_xor(m, 32); m = (t2 > m) ? t2 : m;
        }

        const unsigned short* bkt = lbkt + rloc * CAP;

        // self row
        uint2 u = *reinterpret_cast<const uint2*>(feat + (size_t)node * D + 4 * c);
        float a0 = bfLO(u.x), a1 = bfHI(u.x);
        float a2 = bfLO(u.y), a3 = bfHI(u.y);

        // idx reads are LDS (group-uniform address -> broadcast, no conflict)
        ushort8_t idx = *reinterpret_cast<const ushort8_t*>(bkt);
        for (int r = 0; r < m; ++r) {
            ushort8_t nxt = *reinterpret_cast<const ushort8_t*>(bkt + (r + 1) * 8);
#pragma unroll
            for (int j = 0; j < 8; ++j) {
                uint2 v = *reinterpret_cast<const uint2*>(
                    feat + (size_t)idx[j] * D + 4 * c);
                a0 += bfLO(v.x); a1 += bfHI(v.x);
                a2 += bfLO(v.y); a3 += bfHI(v.y);
            }
            idx = nxt;
        }

        uint2 o;
        o.x = (unsigned)f2bf(a0) | ((unsigned)f2bf(a1) << 16);
        o.y = (unsigned)f2bf(a2) | ((unsigned)f2bf(a3) << 16);
        *reinterpret_cast<uint2*>(stw + (b * 4 + g) * STP + 4 * c) = o;
    }
}

// ---------------------------------------------------------------------------
// Fused bucket-build + gather + MLP layer 1 via MFMA (m89/m91 layouts).
// ---------------------------------------------------------------------------
__global__ __launch_bounds__(256) void gmlp_kernel(
    const unsigned short* __restrict__ feat,   // node features (bf16 rows)
    const int*            __restrict__ bincnt,
    const unsigned*       __restrict__ binbuf,
    const unsigned short* __restrict__ wAb,
    const float*          __restrict__ bA,
    const unsigned short* __restrict__ wBb,
    const float*          __restrict__ bB,
    unsigned short*       __restrict__ outp)
{
    __shared__ int lc[64];
    __shared__ __align__(16) unsigned short lbkt[64 * CAP + 16];  // 8.2 KB
    __shared__ __align__(16) unsigned short st[4][16 * STP];      // 9.2 KB

    const int t    = threadIdx.x;
    const int wv   = t >> 6;
    const int lane = t & 63;
    const int quad = lane >> 4;
    const int col  = lane & 15;

    const int bn0 = blockIdx.x * 64;
    const int n0  = bn0 + wv * 16;

    build_bucket64(bincnt, binbuf, lbkt, lc, bn0, t);

    if (n0 >= N_NODES) return;                   // after barriers: safe

    float bAl[4], bBl[4];
#pragma unroll
    for (int tt = 0; tt < 4; ++tt) {
        bAl[tt] = bA[tt * 16 + col];
        bBl[tt] = bB[tt * 16 + col];
    }

    short8 WA[4][2], WB[4][2];
#pragma unroll
    for (int tt = 0; tt < 4; ++tt)
#pragma unroll
        for (int k = 0; k < 2; ++k) {
            WA[tt][k] = *reinterpret_cast<const short8*>(
                wAb + (tt * 16 + col) * D + k * 32 + quad * 8);
            WB[tt][k] = *reinterpret_cast<const short8*>(
                wBb + (tt * 16 + col) * D + k * 32 + quad * 8);
        }

    unsigned short* stw = &st[wv][0];

    gather16_lds(feat, lbkt, lc, stw, bn0, wv, lane);

    short8 A0 = *reinterpret_cast<const short8*>(stw + col * STP + 0 * 32 + quad * 8);
    short8 A1 = *reinterpret_cast<const short8*>(stw + col * STP + 1 * 32 + quad * 8);

#pragma unroll
    for (int tt = 0; tt < 4; ++tt) {
        floatx4 c = {0.0f, 0.0f, 0.0f, 0.0f};
        c = __builtin_amdgcn_mfma_f32_16x16x32_bf16(A0, WA[tt][0], c, 0, 0, 0);
        c = __builtin_amdgcn_mfma_f32_16x16x32_bf16(A1, WA[tt][1], c, 0, 0, 0);
#pragma unroll
        for (int r = 0; r < 4; ++r) {
            float v = fmaxf(c[r] + bAl[tt], 0.0f);
            stw[(quad * 4 + r) * STP + tt * 16 + col] = f2bf(v);
        }
    }

    short8 T0 = *reinterpret_cast<const short8*>(stw + col * STP + 0 * 32 + quad * 8);
    short8 T1 = *reinterpret_cast<const short8*>(stw + col * STP + 1 * 32 + quad * 8);

#pragma unroll
    for (int tt = 0; tt < 4; ++tt) {
        floatx4 c = {0.0f, 0.0f, 0.0f, 0.0f};
        c = __builtin_amdgcn_mfma_f32_16x16x32_bf16(T0, WB[tt][0], c, 0, 0, 0);
        c = __builtin_amdgcn_mfma_f32_16x16x32_bf16(T1, WB[tt][1], c, 0, 0, 0);
#pragma unroll
        for (int r = 0; r < 4; ++r) {
            float v = fmaxf(c[r] + bBl[tt], 0.0f);
            outp[(size_t)(n0 + quad * 4 + r) * D + tt * 16 + col] = f2bf(v);
        }
    }
}

// ---------------------------------------------------------------------------
// Fused bucket-build + gather + MLP layer 2 + mean-pool numerator.
// ---------------------------------------------------------------------------
__global__ __launch_bounds__(256) void g2mlp_pool_kernel(
    const unsigned short* __restrict__ feat,   // h1 (layer-1 output)
    const int*            __restrict__ bincnt,
    const unsigned*       __restrict__ binbuf,
    const unsigned short* __restrict__ wAb,
    const float*          __restrict__ bA,
    const unsigned short* __restrict__ wBb,
    const float*          __restrict__ bB,
    const int*            __restrict__ batch,  // [N] sorted
    float*                __restrict__ psum)   // [B,64] zero-initialized
{
    __shared__ int lc[64];
    __shared__ __align__(16) unsigned short lbkt[64 * CAP + 16];
    __shared__ __align__(16) unsigned short st[4][16 * STP];
    __shared__ float pt[64][D + 1];            // block's 64-node output tile
    __shared__ int   sbatch[64];

    const int t    = threadIdx.x;
    const int wv   = t >> 6;
    const int lane = t & 63;
    const int quad = lane >> 4;
    const int col  = lane & 15;

    const int bn0 = blockIdx.x * 64;
    const int n0  = bn0 + wv * 16;
    const bool active = (n0 < N_NODES);

    if (t < 64) {
        int n = bn0 + t;
        sbatch[t] = (n < N_NODES) ? batch[n] : -1;
    }
    // (sbatch covered by build_bucket64's first __syncthreads)

    build_bucket64(bincnt, binbuf, lbkt, lc, bn0, t);

    if (active) {
        float bAl[4], bBl[4];
#pragma unroll
        for (int tt = 0; tt < 4; ++tt) {
            bAl[tt] = bA[tt * 16 + col];
            bBl[tt] = bB[tt * 16 + col];
        }

        short8 WA[4][2], WB[4][2];
#pragma unroll
        for (int tt = 0; tt < 4; ++tt)
#pragma unroll
            for (int k = 0; k < 2; ++k) {
                WA[tt][k] = *reinterpret_cast<const short8*>(
                    wAb + (tt * 16 + col) * D + k * 32 + quad * 8);
                WB[tt][k] = *reinterpret_cast<const short8*>(
                    wBb + (tt * 16 + col) * D + k * 32 + quad * 8);
            }

        unsigned short* stw = &st[wv][0];

        gather16_lds(feat, lbkt, lc, stw, bn0, wv, lane);

        short8 A0 = *reinterpret_cast<const short8*>(stw + col * STP + 0 * 32 + quad * 8);
        short8 A1 = *reinterpret_cast<const short8*>(stw + col * STP + 1 * 32 + quad * 8);

#pragma unroll
        for (int tt = 0; tt < 4; ++tt) {
            floatx4 c = {0.0f, 0.0f, 0.0f, 0.0f};
            c = __builtin_amdgcn_mfma_f32_16x16x32_bf16(A0, WA[tt][0], c, 0, 0, 0);
            c = __builtin_amdgcn_mfma_f32_16x16x32_bf16(A1, WA[tt][1], c, 0, 0, 0);
#pragma unroll
            for (int r = 0; r < 4; ++r) {
                float v = fmaxf(c[r] + bAl[tt], 0.0f);
                stw[(quad * 4 + r) * STP + tt * 16 + col] = f2bf(v);
            }
        }

        short8 T0 = *reinterpret_cast<const short8*>(stw + col * STP + 0 * 32 + quad * 8);
        short8 T1 = *reinterpret_cast<const short8*>(stw + col * STP + 1 * 32 + quad * 8);

#pragma unroll
        for (int tt = 0; tt < 4; ++tt) {
            floatx4 c = {0.0f, 0.0f, 0.0f, 0.0f};
            c = __builtin_amdgcn_mfma_f32_16x16x32_bf16(T0, WB[tt][0], c, 0, 0, 0);
            c = __builtin_amdgcn_mfma_f32_16x16x32_bf16(T1, WB[tt][1], c, 0, 0, 0);
#pragma unroll
            for (int r = 0; r < 4; ++r) {
                float v = fmaxf(c[r] + bBl[tt], 0.0f);
                pt[wv * 16 + quad * 4 + r][tt * 16 + col] = v;
            }
        }
    } else {
        // inactive wave: zero its tile rows so the reduce sees zeros
        for (int c2 = 0; c2 < 4; ++c2)
#pragma unroll
            for (int r = 0; r < 4; ++r)
                pt[wv * 16 + quad * 4 + r][c2 * 16 + col] = 0.0f;
    }
    __syncthreads();

    // segmented reduce: thread (q,d) sums rows q*16..q*16+15 of dim d,
    // flushing one atomicAdd per graph run (sorted batch => few runs).
    int q = t >> 6;
    int d = t & 63;
    float acc = 0.0f;
    int curg = sbatch[q * 16];
#pragma unroll
    for (int r = 0; r < 16; ++r) {
        int row = q * 16 + r;
        int g2 = sbatch[row];
        float v = pt[row][d];
        if (g2 != curg) {
            if (curg >= 0) atomicAdd(&psum[curg * D + d], acc);
            acc = 0.0f;
            curg = g2;
        }
        acc += v;
    }
    if (curg >= 0) atomicAdd(&psum[curg * D + d], acc);
}

// ---------------------------------------------------------------------------
// Head: mean from psum + counts, single-step LSTM + FC + softmax.
// ---------------------------------------------------------------------------
__device__ __forceinline__ int lower_bound_dev(const int* a, int n, int v)
{
    int lo = 0, hi = n;
    while (lo < hi) {
        int m = (lo + hi) >> 1;
        if (a[m] < v) lo = m + 1; else hi = m;
    }
    return lo;
}

__device__ __forceinline__ float sigmoidf_(float x) { return 1.0f / (1.0f + expf(-x)); }

__global__ __launch_bounds__(512) void head_kernel(
    const float* __restrict__ psum,   // [B,64] pooled sums
    const int*   __restrict__ batch,  // [N]
    const float* __restrict__ w_ih,
    const float* __restrict__ w_hh,
    const float* __restrict__ b_ih,
    const float* __restrict__ b_hh,
    const float* __restrict__ fc_w,
    const float* __restrict__ fc_b,
    const float* __restrict__ h0,
    const float* __restrict__ c0,
    float*       __restrict__ out_probs,
    float*       __restrict__ out_h1,
    float*       __restrict__ out_c1)
{
    int b = blockIdx.x;
    int j = threadIdx.x;

    __shared__ float sp[D];
    __shared__ float sh[HL];
    __shared__ float gates[4 * HL];
    __shared__ float sh1[HL];
    __shared__ float slog[OUT];

    if (j < D) {
        int start = lower_bound_dev(batch, N_NODES, b);
        int end   = lower_bound_dev(batch, N_NODES, b + 1);
        sp[j] = psum[b * D + j] / fmaxf((float)(end - start), 1.0f);
    } else if (j < D + HL) {
        sh[j - D] = h0[b * HL + (j - D)];
    }
    __syncthreads();

    {
        float acc = b_ih[j] + b_hh[j];
#pragma unroll
        for (int k = 0; k < D; ++k)  acc = fmaf(sp[k], w_ih[j * D + k], acc);
#pragma unroll
        for (int k = 0; k < HL; ++k) acc = fmaf(sh[k], w_hh[j * HL + k], acc);
        gates[j] = acc;
    }
    __syncthreads();

    if (j < HL) {
        float ig = gates[j];
        float fg = gates[HL + j];
        float gg = gates[2 * HL + j];
        float og = gates[3 * HL + j];
        float c  = sigmoidf_(fg) * c0[b * HL + j] + sigmoidf_(ig) * tanhf(gg);
        float hv = sigmoidf_(og) * tanhf(c);
        out_c1[b * HL + j] = c;
        out_h1[b * HL + j] = hv;
        sh1[j] = hv;
    }
    __syncthreads();

    if (j < OUT) {
        float a = fc_b[j];
#pragma unroll
        for (int k = 0; k < HL; ++k) a = fmaf(sh1[k], fc_w[j * HL + k], a);
        slog[j] = a;
    }
    __syncthreads();

    if (j < OUT) {
        float m = -1e30f;
#pragma unroll
        for (int k = 0; k < OUT; ++k) m = fmaxf(m, slog[k]);
        float s = 0.0f;
#pragma unroll
        for (int k = 0; k < OUT; ++k) s += expf(slog[k] - m);
        out_probs[b * OUT + j] = expf(slog[j] - m) / s;
    }
}

// ---------------------------------------------------------------------------
extern "C" void kernel_launch(void* const* d_in, const int* in_sizes, int n_in,
                              void* d_out, int out_size, void* d_ws, size_t ws_size,
                              hipStream_t stream)
{
    const float* x     = (const float*)d_in[0];
    const int*   ei    = (const int*)  d_in[1];
    const int*   batch = (const int*)  d_in[2];
    const float* w1    = (const float*)d_in[3];
    const float* b1    = (const float*)d_in[4];
    const float* w2    = (const float*)d_in[5];
    const float* b2    = (const float*)d_in[6];
    const float* w3    = (const float*)d_in[7];
    const float* b3    = (const float*)d_in[8];
    const float* w4    = (const float*)d_in[9];
    const float* b4    = (const float*)d_in[10];
    const float* w_ih  = (const float*)d_in[11];
    const float* w_hh  = (const float*)d_in[12];
    const float* b_ih  = (const float*)d_in[13];
    const float* b_hh  = (const float*)d_in[14];
    const float* fc_w  = (const float*)d_in[15];
    const float* fc_b  = (const float*)d_in[16];
    const float* h0    = (const float*)d_in[17];
    const float* c0    = (const float*)d_in[18];

    // workspace layout (~13 MB); xb/h1 have N+16 rows (row ZROW = 0)
    const size_t NR = (size_t)N_NODES + 16;
    int* bincnt = (int*)d_ws;                                 // 256 ints
    unsigned* binbuf = (unsigned*)(bincnt + 256);             // BINS*BCAP
    unsigned short* xb = (unsigned short*)(binbuf + (size_t)BINS * BCAP);
    unsigned short* h1 = xb + NR * D;                         // [NR,64] mlp1 out
    unsigned short* wb = h1 + NR * D;                         // 4 x [64,64] bf16
    float* psum = (float*)(wb + 4 * D * D);                   // [B,64]

    float* out_probs = (float*)d_out;
    float* out_h1    = out_probs + B * OUT;
    float* out_c1    = out_h1 + B * HL;

    // ---- bincnt zero (1 KB) + fused prologue (binA || cvt || init) ----
    hipMemsetAsync(bincnt, 0, 256 * sizeof(int), stream);
    fused_pro_kernel<<<AB + CB + 1, 256, 0, stream>>>(
        ei, bincnt, binbuf, x, xb, w1, w2, w3, w4, wb, h1, psum);

    // ---- layer 1 (fused bucket-build + gather + MLP) ----
    gmlp_kernel<<<MB, 256, 0, stream>>>(xb, bincnt, binbuf,
                                        wb, b1, wb + 4096, b2, h1);

    // ---- layer 2 (fused bucket-build + gather + MLP + pool) ----
    g2mlp_pool_kernel<<<MB, 256, 0, stream>>>(h1, bincnt, binbuf,
                                              wb + 8192, b3, wb + 12288, b4,
                                              batch, psum);

    // ---- head ----
    head_kernel<<<B, 512, 0, stream>>>(psum, batch, w_ih, w_hh, b_ih, b_hh,
                                       fc_w, fc_b, h0, c0,
                                       out_probs, out_h1, out_c1);
}